// Round 7
// baseline (182.323 us; speedup 1.0000x reference)
//
#include <hip/hip_runtime.h>
#include <math.h>

// GCN link predictor, sparse-cone evaluation (round 9).
// Round-8 post-mortem: 77 -> 54.6 us. Phase work ~8-12 us; the 5 grid
// barriers still cost ~8 us each (skew + LLC poll + post-fence cold refill).
// This round:
//  - 5 barriers -> 3; last one arrive-only for blocks!=0 (they exit).
//    P4 agg / P5 h1-GEMM / P6 tail all run in block 0 with __syncthreads.
//  - GRID 128->256 (2048 waves): scan iterations/thread 6->3.
//  - memset 1.5MB -> 42KB: deg zeroed grid-stride in P1; agg1e zeroed by
//    block 0 (nf1*64 floats) right before use, agent-scope to avoid stale-L1.
//
// Phases:
//  P1  (all) zero deg; scan dst: e1 edges; register F1            -- B1 --
//  P2  (all) scan dst: e2 edges (dst in F1); need-bits src(e2)    -- B2 --
//  P3  (all) scan dst: deg[d]++ if need-bit[d]                    -- B3 --
//      blocks!=0: arrive & exit.  block 0: wait, then:
//  P4  zero agg1e[0..nf1*CH); edge-parallel atomic agg            (sync)
//  P5  per-F1-row GEMM: h1 = relu((agg1e + dinv^2 x) @ W1 + b1)   (sync)
//  P6  layer-2 agg over e1 (8-wave) + @W2+b2, relu, fc, sigmoid

#define CH 64
#define E1CAP 4096
#define F1CAP (E1CAP + 2)
#define E2CAP 131072
#define GRID 256
#define BLK 512
#define NWAVE (BLK / 64)
#define SPIN_MAX (1 << 20)

struct Params {
    const float* x;
    const int* src; const int* dst; const int* np_;
    const float* W1; const float* b1;
    const float* W2; const float* b2;
    const float* fcW; const float* fcb;
    int* bar;          // [16*b] = block b arrival generation (64B stride)
    int* ctrl;         // [0]=cnt_e1 [1]=cnt_e2 [2]=nf1
    int* deg;
    unsigned* bmF1; unsigned* bmNd;
    int* pos1; int* e1s; int* e1d; int* F1;
    int* e2s; int* e2d; float* h1; float* agg1e;
    float* out;
    int E; int N; int bmN;
};

__device__ __forceinline__ float dinv_of(int degv) {
    return rsqrtf((float)(degv + 1));
}

__device__ __forceinline__ void st_agent(int* p, int v) {
    __hip_atomic_store(p, v, __ATOMIC_RELAXED, __HIP_MEMORY_SCOPE_AGENT);
}
__device__ __forceinline__ void st_agent_f(float* p, float v) {
    __hip_atomic_store(p, v, __ATOMIC_RELAXED, __HIP_MEMORY_SCOPE_AGENT);
}
__device__ __forceinline__ int ld_agent(const int* p) {
    return __hip_atomic_load((int*)p, __ATOMIC_RELAXED, __HIP_MEMORY_SCOPE_AGENT);
}
__device__ __forceinline__ float ld_agent_f(const float* p) {
    return __hip_atomic_load((float*)p, __ATOMIC_RELAXED, __HIP_MEMORY_SCOPE_AGENT);
}

// Arrival half of the barrier: publish writes + store this block's flag.
__device__ __forceinline__ void gbar_arrive(int* bar, int phase) {
    __syncthreads();
    if (threadIdx.x == 0) {
        __builtin_amdgcn_fence(__ATOMIC_RELEASE, "agent");
        st_agent(&bar[blockIdx.x << 4], phase);
    }
}

// Completion half: wave 0 polls all 256 flags (4/lane); acquire fence.
// Bounded spin: pathology degrades to a wrong answer, not a GPU hang.
__device__ __forceinline__ void gbar_wait(int* bar, int phase) {
    if (threadIdx.x < 64) {
        const int l = threadIdx.x;
        for (int it = 0; ; ++it) {
            int a = ld_agent(&bar[l << 4]);
            int b = ld_agent(&bar[(l + 64) << 4]);
            int c = ld_agent(&bar[(l + 128) << 4]);
            int d = ld_agent(&bar[(l + 192) << 4]);
            int m = min(min(a, b), min(c, d));
            if (__all(m >= phase) || it > SPIN_MAX) break;
            __builtin_amdgcn_s_sleep(1);
        }
    }
    if (threadIdx.x == 0)
        __builtin_amdgcn_fence(__ATOMIC_ACQUIRE, "agent");
    __syncthreads();
}

__device__ __forceinline__ void gbar(int* bar, int phase) {
    gbar_arrive(bar, phase);
    gbar_wait(bar, phase);
}

__device__ __forceinline__ void reg_node(int u, unsigned* bmF1, unsigned* bmNd,
                                         int* ctrl, int* F1, int* pos1) {
    unsigned bit = 1u << (u & 31);
    unsigned old = atomicOr(&bmF1[u >> 5], bit);
    if (!(old & bit)) {
        atomicOr(&bmNd[u >> 5], bit);
        int i = atomicAdd(&ctrl[2], 1);
        st_agent(&F1[i], u);
        st_agent(&pos1[u], i);
    }
}

// P1: zero deg (grid-stride, used first in P3) + e1 collection + F1 reg.
__device__ __forceinline__ void phase_e1f1(int gid, int gsz,
                                           const int* __restrict__ src,
                                           const int* __restrict__ dst, int E,
                                           int N, int* deg,
                                           int p0, int p1, int* ctrl,
                                           int* e1s, int* e1d,
                                           unsigned* bmF1, unsigned* bmNd,
                                           int* F1, int* pos1) {
    for (int i = gid; i < N; i += gsz) st_agent(&deg[i], 0);
    if (gid == 0) {
        reg_node(p0, bmF1, bmNd, ctrl, F1, pos1);
        if (p1 != p0) reg_node(p1, bmF1, bmNd, ctrl, F1, pos1);
    }
    const int nvec = E >> 2;
    const int4* dst4 = (const int4*)dst;
    for (int i = gid; i < nvec; i += gsz) {
        int4 d4 = dst4[i];
        int ds[4] = {d4.x, d4.y, d4.z, d4.w};
#pragma unroll
        for (int k = 0; k < 4; k++) {
            int d = ds[k];
            if (d == p0 || d == p1) {
                int s = src[i * 4 + k];
                int idx = atomicAdd(&ctrl[0], 1);
                if (idx < E1CAP) { st_agent(&e1s[idx], s); st_agent(&e1d[idx], d); }
                reg_node(s, bmF1, bmNd, ctrl, F1, pos1);
            }
        }
    }
    for (int e = (nvec << 2) + gid; e < E; e += gsz) {
        int d = dst[e];
        if (d == p0 || d == p1) {
            int s = src[e];
            int idx = atomicAdd(&ctrl[0], 1);
            if (idx < E1CAP) { st_agent(&e1s[idx], s); st_agent(&e1d[idx], d); }
            reg_node(s, bmF1, bmNd, ctrl, F1, pos1);
        }
    }
}

__device__ __forceinline__ void phase_e2(int gid, int gsz,
                                         const int* __restrict__ src,
                                         const int* __restrict__ dst, int E,
                                         const unsigned* __restrict__ bmF1,
                                         unsigned* bmNd, int* ctrl,
                                         int* e2s, int* e2d) {
    const int nvec = E >> 2;
    const int4* dst4 = (const int4*)dst;
    for (int i = gid; i < nvec; i += gsz) {
        int4 d4 = dst4[i];
        int ds[4] = {d4.x, d4.y, d4.z, d4.w};
#pragma unroll
        for (int k = 0; k < 4; k++) {
            int d = ds[k];
            if ((bmF1[d >> 5] >> (d & 31)) & 1u) {
                int s = src[i * 4 + k];
                atomicOr(&bmNd[s >> 5], 1u << (s & 31));
                int idx = atomicAdd(&ctrl[1], 1);
                if (idx < E2CAP) { st_agent(&e2s[idx], s); st_agent(&e2d[idx], d); }
            }
        }
    }
    for (int e = (nvec << 2) + gid; e < E; e += gsz) {
        int d = dst[e];
        if ((bmF1[d >> 5] >> (d & 31)) & 1u) {
            int s = src[e];
            atomicOr(&bmNd[s >> 5], 1u << (s & 31));
            int idx = atomicAdd(&ctrl[1], 1);
            if (idx < E2CAP) { st_agent(&e2s[idx], s); st_agent(&e2d[idx], d); }
        }
    }
}

__device__ __forceinline__ void phase_deg(int gid, int gsz,
                                          const int* __restrict__ dst, int E,
                                          const unsigned* __restrict__ bmNd,
                                          int* deg) {
    const int nvec = E >> 2;
    const int4* dst4 = (const int4*)dst;
    for (int i = gid; i < nvec; i += gsz) {
        int4 d4 = dst4[i];
        int ds[4] = {d4.x, d4.y, d4.z, d4.w};
#pragma unroll
        for (int k = 0; k < 4; k++) {
            int d = ds[k];
            if ((bmNd[d >> 5] >> (d & 31)) & 1u) atomicAdd(&deg[d], 1);
        }
    }
    for (int e = (nvec << 2) + gid; e < E; e += gsz) {
        int d = dst[e];
        if ((bmNd[d >> 5] >> (d & 31)) & 1u) atomicAdd(&deg[d], 1);
    }
}

// ---- block-0-only tail (post-B3): P4 agg, P5 h1 GEMM, P6 output ----
// agg1e discipline: zero via agent stores, accumulate via device-scope
// atomics (act at LLC), read via agent loads -> no stale-L1 copies.
__device__ __forceinline__ void block0_tail(int tid,
                                            const float* __restrict__ x,
                                            const float* __restrict__ W1,
                                            const float* __restrict__ b1,
                                            const float* __restrict__ W2,
                                            const float* __restrict__ b2,
                                            const float* __restrict__ fcW,
                                            const float* __restrict__ fcb,
                                            const int* __restrict__ np_,
                                            const int* __restrict__ ctrl,
                                            const int* __restrict__ deg,
                                            const int* __restrict__ pos1,
                                            const int* __restrict__ F1,
                                            const int* __restrict__ e1s,
                                            const int* __restrict__ e1d,
                                            const int* __restrict__ e2s,
                                            const int* __restrict__ e2d,
                                            float* __restrict__ agg1e,
                                            float* __restrict__ h1,
                                            float* __restrict__ out,
                                            float (*a)[CH], float (*a2p)[CH],
                                            float (*a2)[CH], float* partial) {
    const int nf1  = min(ctrl[2], F1CAP);
    const int cnt2 = min(ctrl[1], E2CAP);
    const int cnt1 = min(ctrl[0], E1CAP);
    const int w = tid >> 6, j = tid & 63;

    // P4a: zero the live part of agg1e
    for (int i = tid; i < nf1 * CH; i += BLK) st_agent_f(&agg1e[i], 0.f);
    __syncthreads();
    // P4b: edge-parallel aggregation (atomics at LLC)
    {
        int total = cnt2 << 6;
        for (int idx = tid; idx < total; idx += BLK) {
            int e = idx >> 6, c = idx & 63;
            int s = e2s[e], u = e2d[e];
            float nrm = dinv_of(deg[s]) * dinv_of(deg[u]);
            atomicAdd(&agg1e[pos1[u] * CH + c], nrm * x[(size_t)s * CH + c]);
        }
    }
    __syncthreads();
    // P5: one F1 row per wave; GEMM row @ W1 + b1, relu -> h1 (plain stores,
    // block-local from here on)
    for (int i = w; i < nf1; i += NWAVE) {
        int u = F1[i];
        float du = dinv_of(deg[u]);
        a[w][j] = ld_agent_f(&agg1e[i * CH + j]) + du * du * x[(size_t)u * CH + j];
        float sum = b1[j];
#pragma unroll
        for (int k = 0; k < CH; k++) sum += a[w][k] * W1[k * CH + j];
        h1[i * CH + j] = fmaxf(sum, 0.f);
    }
    __syncthreads();
    // P6: layer-2 aggregation (4 waves per endpoint, stride-4 over e1)
    {
        int t = w >> 2, sub = w & 3;
        int pp = np_[t];
        float dp = dinv_of(deg[pp]);
        float acc = (sub == 0) ? dp * dp * h1[pos1[pp] * CH + j] : 0.f;
        for (int e = sub; e < cnt1; e += 4) {
            if (e1d[e] == pp) {
                int s = e1s[e];
                acc += dinv_of(deg[s]) * dp * h1[pos1[s] * CH + j];
            }
        }
        a2p[w][j] = acc;
    }
    __syncthreads();
    if (tid < 128) {
        int t2 = tid >> 6;
        a2[t2][j] = a2p[t2 * 4][j] + a2p[t2 * 4 + 1][j] +
                    a2p[t2 * 4 + 2][j] + a2p[t2 * 4 + 3][j];
    }
    __syncthreads();
    if (tid < 128) {
        int t2 = tid >> 6;
        float sum = b2[j];
#pragma unroll
        for (int k = 0; k < CH; k++) sum += a2[t2][k] * W2[k * CH + j];
        float v = fmaxf(sum, 0.f);
        float pr = v * fcW[t2 * CH + j];
        for (int off = 32; off > 0; off >>= 1) pr += __shfl_down(pr, off);
        if (j == 0) partial[t2] = pr;
    }
    __syncthreads();
    if (tid == 0) {
        float z = partial[0] + partial[1] + fcb[0];
        out[0] = 1.f / (1.f + expf(-z));
    }
}

__global__ __launch_bounds__(BLK, 1) void k_fused(Params p) {
    __shared__ float a[NWAVE][CH];
    __shared__ float a2p[NWAVE][CH];
    __shared__ float a2[2][CH];
    __shared__ float partial[2];
    const int gid = blockIdx.x * BLK + threadIdx.x;
    const int gsz = GRID * BLK;

    phase_e1f1(gid, gsz, p.src, p.dst, p.E, p.N, p.deg,
               p.np_[0], p.np_[1], p.ctrl, p.e1s, p.e1d,
               p.bmF1, p.bmNd, p.F1, p.pos1);
    gbar(p.bar, 1);
    phase_e2(gid, gsz, p.src, p.dst, p.E, p.bmF1, p.bmNd, p.ctrl, p.e2s, p.e2d);
    gbar(p.bar, 2);
    phase_deg(gid, gsz, p.dst, p.E, p.bmNd, p.deg);
    gbar_arrive(p.bar, 3);
    if (blockIdx.x != 0) return;     // blocks 1..255 done
    gbar_wait(p.bar, 3);
    block0_tail(threadIdx.x, p.x, p.W1, p.b1, p.W2, p.b2, p.fcW, p.fcb,
                p.np_, p.ctrl, p.deg, p.pos1, p.F1, p.e1s, p.e1d,
                p.e2s, p.e2d, p.agg1e, p.h1, (float*)p.out,
                a, a2p, a2, partial);
}

extern "C" void kernel_launch(void* const* d_in, const int* in_sizes, int n_in,
                              void* d_out, int out_size, void* d_ws, size_t ws_size,
                              hipStream_t stream) {
    const float* x   = (const float*)d_in[0];
    const int*   ei  = (const int*)d_in[1];
    const int*   np_ = (const int*)d_in[2];

    const int N = in_sizes[0] / CH;
    const int E = in_sizes[1] / 2;
    const int bmN = (N + 31) / 32;

    char* w = (char*)d_ws;
    size_t off = 0;
    auto alloc = [&](size_t bytes) {
        size_t o = off;
        off = (off + bytes + 255) & ~((size_t)255);
        return o;
    };
    // --- zeroed region (~42 KB: barrier flags + ctrl + bitmaps) ---
    size_t o_bar  = alloc((size_t)GRID * 16 * 4);   // 64B-strided flags
    size_t o_ctrl = alloc(64);                      // cnt_e1, cnt_e2, nf1
    size_t o_bmF1 = alloc((size_t)bmN * 4);
    size_t o_bmNd = alloc((size_t)bmN * 4);
    size_t zero_end = off;
    // --- uninitialized region (deg zeroed in P1; agg1e zeroed in P4a) ---
    size_t o_deg  = alloc((size_t)N * 4);
    size_t o_pos  = alloc((size_t)N * 4);
    size_t o_e1s  = alloc((size_t)E1CAP * 4);
    size_t o_e1d  = alloc((size_t)E1CAP * 4);
    size_t o_F1   = alloc((size_t)F1CAP * 4);
    size_t o_e2s  = alloc((size_t)E2CAP * 4);
    size_t o_e2d  = alloc((size_t)E2CAP * 4);
    size_t o_h1   = alloc((size_t)F1CAP * CH * 4);
    size_t o_agg  = alloc((size_t)F1CAP * CH * 4);
    (void)ws_size;

    Params p;
    p.x    = x;
    p.src  = ei;
    p.dst  = ei + E;
    p.np_  = np_;
    p.W1   = (const float*)d_in[3];
    p.b1   = (const float*)d_in[4];
    p.W2   = (const float*)d_in[5];
    p.b2   = (const float*)d_in[6];
    p.fcW  = (const float*)d_in[7];
    p.fcb  = (const float*)d_in[8];
    p.bar   = (int*)(w + o_bar);
    p.ctrl  = (int*)(w + o_ctrl);
    p.bmF1  = (unsigned*)(w + o_bmF1);
    p.bmNd  = (unsigned*)(w + o_bmNd);
    p.deg   = (int*)(w + o_deg);
    p.pos1  = (int*)(w + o_pos);
    p.e1s   = (int*)(w + o_e1s);
    p.e1d   = (int*)(w + o_e1d);
    p.F1    = (int*)(w + o_F1);
    p.e2s   = (int*)(w + o_e2s);
    p.e2d   = (int*)(w + o_e2d);
    p.h1    = (float*)(w + o_h1);
    p.agg1e = (float*)(w + o_agg);
    p.out  = (float*)d_out;
    p.E = E; p.N = N; p.bmN = bmN;

    (void)hipMemsetAsync(d_ws, 0, zero_end, stream);   // ~42 KB

    k_fused<<<GRID, BLK, 0, stream>>>(p);
}

// Round 8
// 132.724 us; speedup vs baseline: 1.3737x; 1.3737x over previous
//
#include <hip/hip_runtime.h>
#include <math.h>

// GCN link predictor, sparse-cone evaluation (round 10).
// Round-9 post-mortem: REGRESSION 54.6 -> 105 us. Serializing the agg gather
// (HBM-latency-bound, ~550 scattered 256B x-rows) onto one block exposed
// ~20-30 us of memory latency; in-kernel deg zeroing + GRID=256 made it
// worse. Reverted to the round-8 skeleton (grid-wide everything, GRID=128,
// memset'd deg/agg1e). New attack: the ~8 us/barrier unit cost.
//   Fenceless barriers: ALL mutable cross-block state (ctrl, bitmaps, deg,
//   e1/e2/F1/pos1, agg1e, h1) is accessed ONLY via agent-scope (LLC)
//   atomics/loads/stores -> no cached copies exist -> no release/acquire
//   cache-wide fences needed. __syncthreads() drains vmem (compiler emits
//   s_waitcnt vmcnt(0) before s_barrier), so flag stores publish correctly.
//   Read-only inputs (dst/src/x/W*) stay cached across phases (no invals).
//
// Phases (one plain launch, 5 fenceless flag barriers):
//  P1  scan dst: e1 edges; register F1                       -- B1 --
//  P2  scan dst: e2 edges (dst in F1); need-bits src(e2)     -- B2 --
//  P3  scan dst: deg[d]++ if need-bit[d]                     -- B3 --
//  P4  edge-parallel agg incl. self-loop virtual edges       -- B4 --
//      (blocks >= 8 arrive with final flag and exit)
//  P5  per-F1-row GEMM on blocks 0..7                        -- B5 --
//  P6  block 0: layer-2 agg + @W2+b2, relu, fc, sigmoid

#define CH 64
#define E1CAP 4096
#define F1CAP (E1CAP + 2)
#define E2CAP 131072
#define GRID 128
#define BLK 512
#define NWAVE (BLK / 64)
#define NP5 8
#define SPIN_MAX (1 << 20)

struct Params {
    const float* x;
    const int* src; const int* dst; const int* np_;
    const float* W1; const float* b1;
    const float* W2; const float* b2;
    const float* fcW; const float* fcb;
    int* bar;          // [16*b] = block b flag (64B stride), monotone
    int* ctrl;         // [0]=cnt_e1 [1]=cnt_e2 [2]=nf1
    int* deg;
    unsigned* bmF1; unsigned* bmNd;
    int* pos1; int* e1s; int* e1d; int* F1;
    int* e2s; int* e2d; float* h1; float* agg1e;
    float* out;
    int E; int N; int bmN;
};

__device__ __forceinline__ float dinv_of(int degv) {
    return rsqrtf((float)(degv + 1));
}

__device__ __forceinline__ void st_agent(int* p, int v) {
    __hip_atomic_store(p, v, __ATOMIC_RELAXED, __HIP_MEMORY_SCOPE_AGENT);
}
__device__ __forceinline__ void st_agent_f(float* p, float v) {
    __hip_atomic_store(p, v, __ATOMIC_RELAXED, __HIP_MEMORY_SCOPE_AGENT);
}
__device__ __forceinline__ int ld_agent(const int* p) {
    return __hip_atomic_load((int*)p, __ATOMIC_RELAXED, __HIP_MEMORY_SCOPE_AGENT);
}
__device__ __forceinline__ unsigned ld_agent_u(const unsigned* p) {
    return __hip_atomic_load((unsigned*)p, __ATOMIC_RELAXED, __HIP_MEMORY_SCOPE_AGENT);
}
__device__ __forceinline__ float ld_agent_f(const float* p) {
    return __hip_atomic_load((float*)p, __ATOMIC_RELAXED, __HIP_MEMORY_SCOPE_AGENT);
}

// Fenceless barrier halves. Correctness relies on the uncached-mutable
// discipline above: no dirty cached data exists, so no wb/inv fences.
// __syncthreads() drains each wave's outstanding vmem ops before the flag
// store. Waits use >= so a block may arrive with its FINAL phase and exit.
__device__ __forceinline__ void gbar_arrive(int* bar, int phase) {
    __syncthreads();
    if (threadIdx.x == 0) {
        asm volatile("" ::: "memory");
        st_agent(&bar[blockIdx.x << 4], phase);
    }
}
__device__ __forceinline__ void gbar_wait(int* bar, int phase) {
    if (threadIdx.x < 64) {
        const int l = threadIdx.x;
        for (int it = 0; ; ++it) {
            int a = ld_agent(&bar[l << 4]);
            int b = ld_agent(&bar[(l + 64) << 4]);
            if (__all(min(a, b) >= phase) || it > SPIN_MAX) break;
            __builtin_amdgcn_s_sleep(1);
        }
    }
    __syncthreads();
}
__device__ __forceinline__ void gbar(int* bar, int phase) {
    gbar_arrive(bar, phase);
    gbar_wait(bar, phase);
}

__device__ __forceinline__ void reg_node(int u, unsigned* bmF1, unsigned* bmNd,
                                         int* ctrl, int* F1, int* pos1) {
    unsigned bit = 1u << (u & 31);
    unsigned old = atomicOr(&bmF1[u >> 5], bit);
    if (!(old & bit)) {
        atomicOr(&bmNd[u >> 5], bit);
        int i = atomicAdd(&ctrl[2], 1);
        st_agent(&F1[i], u);
        st_agent(&pos1[u], i);
    }
}

// P1: e1 collection + F1 registration (dst/src reads cached).
__device__ __forceinline__ void phase_e1f1(int gid, int gsz,
                                           const int* __restrict__ src,
                                           const int* __restrict__ dst, int E,
                                           int p0, int p1, int* ctrl,
                                           int* e1s, int* e1d,
                                           unsigned* bmF1, unsigned* bmNd,
                                           int* F1, int* pos1) {
    if (gid == 0) {
        reg_node(p0, bmF1, bmNd, ctrl, F1, pos1);
        if (p1 != p0) reg_node(p1, bmF1, bmNd, ctrl, F1, pos1);
    }
    const int nvec = E >> 2;
    const int4* dst4 = (const int4*)dst;
    for (int i = gid; i < nvec; i += gsz) {
        int4 d4 = dst4[i];
        int ds[4] = {d4.x, d4.y, d4.z, d4.w};
#pragma unroll
        for (int k = 0; k < 4; k++) {
            int d = ds[k];
            if (d == p0 || d == p1) {
                int s = src[i * 4 + k];
                int idx = atomicAdd(&ctrl[0], 1);
                if (idx < E1CAP) { st_agent(&e1s[idx], s); st_agent(&e1d[idx], d); }
                reg_node(s, bmF1, bmNd, ctrl, F1, pos1);
            }
        }
    }
    for (int e = (nvec << 2) + gid; e < E; e += gsz) {
        int d = dst[e];
        if (d == p0 || d == p1) {
            int s = src[e];
            int idx = atomicAdd(&ctrl[0], 1);
            if (idx < E1CAP) { st_agent(&e1s[idx], s); st_agent(&e1d[idx], d); }
            reg_node(s, bmF1, bmNd, ctrl, F1, pos1);
        }
    }
}

// P2: e2 scan. Bitmap reads are agent-scope (mutable); dst/src cached.
__device__ __forceinline__ void phase_e2(int gid, int gsz,
                                         const int* __restrict__ src,
                                         const int* __restrict__ dst, int E,
                                         const unsigned* __restrict__ bmF1,
                                         unsigned* bmNd, int* ctrl,
                                         int* e2s, int* e2d) {
    const int nvec = E >> 2;
    const int4* dst4 = (const int4*)dst;
    for (int i = gid; i < nvec; i += gsz) {
        int4 d4 = dst4[i];
        int ds[4] = {d4.x, d4.y, d4.z, d4.w};
#pragma unroll
        for (int k = 0; k < 4; k++) {
            int d = ds[k];
            if ((ld_agent_u(&bmF1[d >> 5]) >> (d & 31)) & 1u) {
                int s = src[i * 4 + k];
                atomicOr(&bmNd[s >> 5], 1u << (s & 31));
                int idx = atomicAdd(&ctrl[1], 1);
                if (idx < E2CAP) { st_agent(&e2s[idx], s); st_agent(&e2d[idx], d); }
            }
        }
    }
    for (int e = (nvec << 2) + gid; e < E; e += gsz) {
        int d = dst[e];
        if ((ld_agent_u(&bmF1[d >> 5]) >> (d & 31)) & 1u) {
            int s = src[e];
            atomicOr(&bmNd[s >> 5], 1u << (s & 31));
            int idx = atomicAdd(&ctrl[1], 1);
            if (idx < E2CAP) { st_agent(&e2s[idx], s); st_agent(&e2d[idx], d); }
        }
    }
}

__device__ __forceinline__ void phase_deg(int gid, int gsz,
                                          const int* __restrict__ dst, int E,
                                          const unsigned* __restrict__ bmNd,
                                          int* deg) {
    const int nvec = E >> 2;
    const int4* dst4 = (const int4*)dst;
    for (int i = gid; i < nvec; i += gsz) {
        int4 d4 = dst4[i];
        int ds[4] = {d4.x, d4.y, d4.z, d4.w};
#pragma unroll
        for (int k = 0; k < 4; k++) {
            int d = ds[k];
            if ((ld_agent_u(&bmNd[d >> 5]) >> (d & 31)) & 1u) atomicAdd(&deg[d], 1);
        }
    }
    for (int e = (nvec << 2) + gid; e < E; e += gsz) {
        int d = dst[e];
        if ((ld_agent_u(&bmNd[d >> 5]) >> (d & 31)) & 1u) atomicAdd(&deg[d], 1);
    }
}

// P4: edge-parallel aggregation including self-loop virtual edges.
// One wave per (edge|row), 64 channels across lanes; x reads cached/coalesced.
__device__ __forceinline__ void phase_agg(int gid, int gsz,
                                          const float* __restrict__ x,
                                          const int* __restrict__ deg,
                                          const int* __restrict__ pos1,
                                          const int* __restrict__ ctrl,
                                          const int* __restrict__ e2s,
                                          const int* __restrict__ e2d,
                                          const int* __restrict__ F1,
                                          float* __restrict__ agg1e) {
    int cnt2 = min(ld_agent(&ctrl[1]), E2CAP);
    int nf1  = min(ld_agent(&ctrl[2]), F1CAP);
    int total = (cnt2 + nf1) << 6;
    for (int idx = gid; idx < total; idx += gsz) {
        int e = idx >> 6, c = idx & 63;
        int row; float val;
        if (e < cnt2) {
            int s = ld_agent(&e2s[e]), u = ld_agent(&e2d[e]);
            float nrm = dinv_of(ld_agent(&deg[s])) * dinv_of(ld_agent(&deg[u]));
            row = ld_agent(&pos1[u]);
            val = nrm * x[(size_t)s * CH + c];
        } else {
            int i = e - cnt2;
            int u = ld_agent(&F1[i]);
            float du = dinv_of(ld_agent(&deg[u]));
            row = i;
            val = du * du * x[(size_t)u * CH + c];
        }
        atomicAdd(&agg1e[row * CH + c], val);
    }
}

// P5 (blocks 0..NP5-1): one F1 row per wave; h1 = relu(agg1e @ W1 + b1).
__device__ __forceinline__ void phase_h1g(int blockId, int tid,
                                          const float* __restrict__ W1,
                                          const float* __restrict__ b1,
                                          const int* __restrict__ ctrl,
                                          const float* __restrict__ agg1e,
                                          float* __restrict__ h1,
                                          float (*a)[CH]) {
    int nf1 = min(ld_agent(&ctrl[2]), F1CAP);
    int w = tid >> 6, j = tid & 63;
    for (int i = blockId * NWAVE + w; i < nf1; i += NP5 * NWAVE) {
        a[w][j] = ld_agent_f(&agg1e[i * CH + j]);   // same-wave LDS RAW
        float sum = b1[j];
#pragma unroll
        for (int k = 0; k < CH; k++) sum += a[w][k] * W1[k * CH + j];
        st_agent_f(&h1[i * CH + j], fmaxf(sum, 0.f));
    }
}

// P6 (block 0): layer-2 agg (4 waves/endpoint) + @W2+b2, relu, fc, sigmoid.
__device__ __forceinline__ void phase_tail(int tid,
                                           const float* __restrict__ h1,
                                           const int* __restrict__ deg,
                                           const int* __restrict__ pos1,
                                           const int* __restrict__ np_,
                                           const int* __restrict__ ctrl,
                                           const int* __restrict__ e1s,
                                           const int* __restrict__ e1d,
                                           const float* __restrict__ W2,
                                           const float* __restrict__ b2,
                                           const float* __restrict__ fcW,
                                           const float* __restrict__ fcb,
                                           float* __restrict__ out,
                                           float (*a2p)[CH], float (*a2)[CH],
                                           float* partial) {
    int w = tid >> 6, j = tid & 63;
    int t = w >> 2, sub = w & 3;          // 4 waves per endpoint
    int pp = np_[t];
    float dp = dinv_of(ld_agent(&deg[pp]));
    float acc = (sub == 0) ? dp * dp * ld_agent_f(&h1[ld_agent(&pos1[pp]) * CH + j]) : 0.f;
    int cnt1 = min(ld_agent(&ctrl[0]), E1CAP);
    for (int e = sub; e < cnt1; e += 4) {
        if (ld_agent(&e1d[e]) == pp) {
            int s = ld_agent(&e1s[e]);
            acc += dinv_of(ld_agent(&deg[s])) * dp *
                   ld_agent_f(&h1[ld_agent(&pos1[s]) * CH + j]);
        }
    }
    a2p[w][j] = acc;
    __syncthreads();
    if (tid < 128) {
        int t2 = tid >> 6;
        a2[t2][j] = a2p[t2 * 4][j] + a2p[t2 * 4 + 1][j] +
                    a2p[t2 * 4 + 2][j] + a2p[t2 * 4 + 3][j];
    }
    __syncthreads();
    if (tid < 128) {
        int t2 = tid >> 6;
        float sum = b2[j];
#pragma unroll
        for (int k = 0; k < CH; k++) sum += a2[t2][k] * W2[k * CH + j];
        float v = fmaxf(sum, 0.f);
        float pr = v * fcW[t2 * CH + j];
        for (int off = 32; off > 0; off >>= 1) pr += __shfl_down(pr, off);
        if (j == 0) partial[t2] = pr;
    }
    __syncthreads();
    if (tid == 0) {
        float z = partial[0] + partial[1] + fcb[0];
        out[0] = 1.f / (1.f + expf(-z));
    }
}

__global__ __launch_bounds__(BLK, 1) void k_fused(Params p) {
    __shared__ float a[NWAVE][CH];
    __shared__ float a2p[NWAVE][CH];
    __shared__ float a2[2][CH];
    __shared__ float partial[2];
    const int gid = blockIdx.x * BLK + threadIdx.x;
    const int gsz = GRID * BLK;

    phase_e1f1(gid, gsz, p.src, p.dst, p.E, p.np_[0], p.np_[1], p.ctrl,
               p.e1s, p.e1d, p.bmF1, p.bmNd, p.F1, p.pos1);
    gbar(p.bar, 1);
    phase_e2(gid, gsz, p.src, p.dst, p.E, p.bmF1, p.bmNd, p.ctrl, p.e2s, p.e2d);
    gbar(p.bar, 2);
    phase_deg(gid, gsz, p.dst, p.E, p.bmNd, p.deg);
    gbar(p.bar, 3);
    phase_agg(gid, gsz, p.x, p.deg, p.pos1, p.ctrl, p.e2s, p.e2d, p.F1, p.agg1e);
    if (blockIdx.x >= NP5) {          // no P5/P6 duties: final arrival + exit
        gbar_arrive(p.bar, 5);
        return;
    }
    gbar(p.bar, 4);
    phase_h1g(blockIdx.x, threadIdx.x, p.W1, p.b1, p.ctrl, p.agg1e, p.h1, a);
    gbar_arrive(p.bar, 5);
    if (blockIdx.x != 0) return;
    gbar_wait(p.bar, 5);
    phase_tail(threadIdx.x, p.h1, p.deg, p.pos1, p.np_, p.ctrl, p.e1s, p.e1d,
               p.W2, p.b2, p.fcW, p.fcb, (float*)p.out, a2p, a2, partial);
}

extern "C" void kernel_launch(void* const* d_in, const int* in_sizes, int n_in,
                              void* d_out, int out_size, void* d_ws, size_t ws_size,
                              hipStream_t stream) {
    const float* x   = (const float*)d_in[0];
    const int*   ei  = (const int*)d_in[1];
    const int*   np_ = (const int*)d_in[2];

    const int N = in_sizes[0] / CH;
    const int E = in_sizes[1] / 2;
    const int bmN = (N + 31) / 32;

    char* w = (char*)d_ws;
    size_t off = 0;
    auto alloc = [&](size_t bytes) {
        size_t o = off;
        off = (off + bytes + 255) & ~((size_t)255);
        return o;
    };
    // --- zeroed region (~1.5 MB, fill engine): bar + ctrl + bitmaps + deg
    //     + agg1e ---
    size_t o_bar  = alloc((size_t)GRID * 16 * 4);   // 64B-strided flags
    size_t o_ctrl = alloc(64);                      // cnt_e1, cnt_e2, nf1
    size_t o_bmF1 = alloc((size_t)bmN * 4);
    size_t o_bmNd = alloc((size_t)bmN * 4);
    size_t o_deg  = alloc((size_t)N * 4);
    size_t o_agg  = alloc((size_t)F1CAP * CH * 4);
    size_t zero_end = off;
    // --- uninitialized region ---
    size_t o_pos  = alloc((size_t)N * 4);
    size_t o_e1s  = alloc((size_t)E1CAP * 4);
    size_t o_e1d  = alloc((size_t)E1CAP * 4);
    size_t o_F1   = alloc((size_t)F1CAP * 4);
    size_t o_e2s  = alloc((size_t)E2CAP * 4);
    size_t o_e2d  = alloc((size_t)E2CAP * 4);
    size_t o_h1   = alloc((size_t)F1CAP * CH * 4);
    (void)ws_size;

    Params p;
    p.x    = x;
    p.src  = ei;
    p.dst  = ei + E;
    p.np_  = np_;
    p.W1   = (const float*)d_in[3];
    p.b1   = (const float*)d_in[4];
    p.W2   = (const float*)d_in[5];
    p.b2   = (const float*)d_in[6];
    p.fcW  = (const float*)d_in[7];
    p.fcb  = (const float*)d_in[8];
    p.bar   = (int*)(w + o_bar);
    p.ctrl  = (int*)(w + o_ctrl);
    p.bmF1  = (unsigned*)(w + o_bmF1);
    p.bmNd  = (unsigned*)(w + o_bmNd);
    p.deg   = (int*)(w + o_deg);
    p.agg1e = (float*)(w + o_agg);
    p.pos1  = (int*)(w + o_pos);
    p.e1s   = (int*)(w + o_e1s);
    p.e1d   = (int*)(w + o_e1d);
    p.F1    = (int*)(w + o_F1);
    p.e2s   = (int*)(w + o_e2s);
    p.e2d   = (int*)(w + o_e2d);
    p.h1    = (float*)(w + o_h1);
    p.out  = (float*)d_out;
    p.E = E; p.N = N; p.bmN = bmN;

    (void)hipMemsetAsync(d_ws, 0, zero_end, stream);   // ~1.5 MB

    k_fused<<<GRID, BLK, 0, stream>>>(p);
}

// Round 9
// 127.137 us; speedup vs baseline: 1.4341x; 1.0439x over previous
//
#include <hip/hip_runtime.h>
#include <math.h>

// GCN link predictor, sparse-cone evaluation (round 11).
// Round-10 post-mortem: 54.6 -> 46.9 us (best). Remaining cost model: the
// per-edge AGENT-SCOPE (LLC, uncached) bitmap loads in P2/P3 (1.6M/scan,
// ~600ns, ~2.5 waves/SIMD TLP) and P4's agent-load chains are the phase
// cost. Uncached access is only needed where a cached copy could PREDATE
// the write (none of our read-after-barrier patterns do: kernel-start
// acquire invalidated memset-era lines; atomics/agent-stores don't allocate
// into L1/L2; every buffer's first cached read is post-barrier). This round:
// all post-barrier READS become plain cached loads (bitmap tests -> L1
// hits); writes stay agent-scope/atomic; barrier flags stay agent-scope.
//
// Phases (one plain launch, 5 fenceless flag barriers):
//  P1  scan dst: e1 edges; register F1                       -- B1 --
//  P2  scan dst: e2 edges (dst in bmF1); need-bits src(e2)   -- B2 --
//  P3  scan dst: deg[d]++ if need-bit[d]                     -- B3 --
//  P4  edge-parallel agg incl. self-loop virtual edges       -- B4 --
//      (blocks >= 8 arrive with final flag and exit)
//  P5  per-F1-row GEMM on blocks 0..7                        -- B5 --
//  P6  block 0: layer-2 agg + @W2+b2, relu, fc, sigmoid

#define CH 64
#define E1CAP 4096
#define F1CAP (E1CAP + 2)
#define E2CAP 131072
#define GRID 128
#define BLK 512
#define NWAVE (BLK / 64)
#define NP5 8
#define SPIN_MAX (1 << 20)

struct Params {
    const float* x;
    const int* src; const int* dst; const int* np_;
    const float* W1; const float* b1;
    const float* W2; const float* b2;
    const float* fcW; const float* fcb;
    int* bar;          // [16*b] = block b flag (64B stride), monotone
    int* ctrl;         // [0]=cnt_e1 [1]=cnt_e2 [2]=nf1
    int* deg;
    unsigned* bmF1; unsigned* bmNd;
    int* pos1; int* e1s; int* e1d; int* F1;
    int* e2s; int* e2d; float* h1; float* agg1e;
    float* out;
    int E; int N; int bmN;
};

__device__ __forceinline__ float dinv_of(int degv) {
    return rsqrtf((float)(degv + 1));
}

__device__ __forceinline__ void st_agent(int* p, int v) {
    __hip_atomic_store(p, v, __ATOMIC_RELAXED, __HIP_MEMORY_SCOPE_AGENT);
}
__device__ __forceinline__ void st_agent_f(float* p, float v) {
    __hip_atomic_store(p, v, __ATOMIC_RELAXED, __HIP_MEMORY_SCOPE_AGENT);
}
__device__ __forceinline__ int ld_agent(const int* p) {
    return __hip_atomic_load((int*)p, __ATOMIC_RELAXED, __HIP_MEMORY_SCOPE_AGENT);
}

// Fenceless barrier halves (see round-10 comment). Flags agent-scope only.
__device__ __forceinline__ void gbar_arrive(int* bar, int phase) {
    __syncthreads();
    if (threadIdx.x == 0) {
        asm volatile("" ::: "memory");
        st_agent(&bar[blockIdx.x << 4], phase);
    }
}
__device__ __forceinline__ void gbar_wait(int* bar, int phase) {
    if (threadIdx.x < 64) {
        const int l = threadIdx.x;
        for (int it = 0; ; ++it) {
            int a = ld_agent(&bar[l << 4]);
            int b = ld_agent(&bar[(l + 64) << 4]);
            if (__all(min(a, b) >= phase) || it > SPIN_MAX) break;
            __builtin_amdgcn_s_sleep(1);
        }
    }
    __syncthreads();
}
__device__ __forceinline__ void gbar(int* bar, int phase) {
    gbar_arrive(bar, phase);
    gbar_wait(bar, phase);
}

__device__ __forceinline__ void reg_node(int u, unsigned* bmF1, unsigned* bmNd,
                                         int* ctrl, int* F1, int* pos1) {
    unsigned bit = 1u << (u & 31);
    unsigned old = atomicOr(&bmF1[u >> 5], bit);
    if (!(old & bit)) {
        atomicOr(&bmNd[u >> 5], bit);
        int i = atomicAdd(&ctrl[2], 1);
        st_agent(&F1[i], u);
        st_agent(&pos1[u], i);
    }
}

// P1: e1 collection + F1 registration (dst/src reads cached; no bitmap reads).
__device__ __forceinline__ void phase_e1f1(int gid, int gsz,
                                           const int* __restrict__ src,
                                           const int* __restrict__ dst, int E,
                                           int p0, int p1, int* ctrl,
                                           int* e1s, int* e1d,
                                           unsigned* bmF1, unsigned* bmNd,
                                           int* F1, int* pos1) {
    if (gid == 0) {
        reg_node(p0, bmF1, bmNd, ctrl, F1, pos1);
        if (p1 != p0) reg_node(p1, bmF1, bmNd, ctrl, F1, pos1);
    }
    const int nvec = E >> 2;
    const int4* dst4 = (const int4*)dst;
    for (int i = gid; i < nvec; i += gsz) {
        int4 d4 = dst4[i];
        int ds[4] = {d4.x, d4.y, d4.z, d4.w};
#pragma unroll
        for (int k = 0; k < 4; k++) {
            int d = ds[k];
            if (d == p0 || d == p1) {
                int s = src[i * 4 + k];
                int idx = atomicAdd(&ctrl[0], 1);
                if (idx < E1CAP) { st_agent(&e1s[idx], s); st_agent(&e1d[idx], d); }
                reg_node(s, bmF1, bmNd, ctrl, F1, pos1);
            }
        }
    }
    for (int e = (nvec << 2) + gid; e < E; e += gsz) {
        int d = dst[e];
        if (d == p0 || d == p1) {
            int s = src[e];
            int idx = atomicAdd(&ctrl[0], 1);
            if (idx < E1CAP) { st_agent(&e1s[idx], s); st_agent(&e1d[idx], d); }
            reg_node(s, bmF1, bmNd, ctrl, F1, pos1);
        }
    }
}

// P2: e2 scan. bmF1 is read-only now (written P1, pre-B1) -> cached loads;
// 12.5KB bitmap becomes L1-resident.
__device__ __forceinline__ void phase_e2(int gid, int gsz,
                                         const int* __restrict__ src,
                                         const int* __restrict__ dst, int E,
                                         const unsigned* __restrict__ bmF1,
                                         unsigned* bmNd, int* ctrl,
                                         int* e2s, int* e2d) {
    const int nvec = E >> 2;
    const int4* dst4 = (const int4*)dst;
    for (int i = gid; i < nvec; i += gsz) {
        int4 d4 = dst4[i];
        int ds[4] = {d4.x, d4.y, d4.z, d4.w};
#pragma unroll
        for (int k = 0; k < 4; k++) {
            int d = ds[k];
            if ((bmF1[d >> 5] >> (d & 31)) & 1u) {
                int s = src[i * 4 + k];
                atomicOr(&bmNd[s >> 5], 1u << (s & 31));
                int idx = atomicAdd(&ctrl[1], 1);
                if (idx < E2CAP) { st_agent(&e2s[idx], s); st_agent(&e2d[idx], d); }
            }
        }
    }
    for (int e = (nvec << 2) + gid; e < E; e += gsz) {
        int d = dst[e];
        if ((bmF1[d >> 5] >> (d & 31)) & 1u) {
            int s = src[e];
            atomicOr(&bmNd[s >> 5], 1u << (s & 31));
            int idx = atomicAdd(&ctrl[1], 1);
            if (idx < E2CAP) { st_agent(&e2s[idx], s); st_agent(&e2d[idx], d); }
        }
    }
}

// P3: deg scan. bmNd read-only now (written P1/P2, pre-B2) -> cached loads.
__device__ __forceinline__ void phase_deg(int gid, int gsz,
                                          const int* __restrict__ dst, int E,
                                          const unsigned* __restrict__ bmNd,
                                          int* deg) {
    const int nvec = E >> 2;
    const int4* dst4 = (const int4*)dst;
    for (int i = gid; i < nvec; i += gsz) {
        int4 d4 = dst4[i];
        int ds[4] = {d4.x, d4.y, d4.z, d4.w};
#pragma unroll
        for (int k = 0; k < 4; k++) {
            int d = ds[k];
            if ((bmNd[d >> 5] >> (d & 31)) & 1u) atomicAdd(&deg[d], 1);
        }
    }
    for (int e = (nvec << 2) + gid; e < E; e += gsz) {
        int d = dst[e];
        if ((bmNd[d >> 5] >> (d & 31)) & 1u) atomicAdd(&deg[d], 1);
    }
}

// P4: edge-parallel aggregation incl. self-loop virtual edges. All reads
// cached (lists/deg/pos1 complete pre-B3); only the accumulate is atomic.
__device__ __forceinline__ void phase_agg(int gid, int gsz,
                                          const float* __restrict__ x,
                                          const int* __restrict__ deg,
                                          const int* __restrict__ pos1,
                                          const int* __restrict__ ctrl,
                                          const int* __restrict__ e2s,
                                          const int* __restrict__ e2d,
                                          const int* __restrict__ F1,
                                          float* __restrict__ agg1e) {
    int cnt2 = min(ctrl[1], E2CAP);
    int nf1  = min(ctrl[2], F1CAP);
    int total = (cnt2 + nf1) << 6;
    for (int idx = gid; idx < total; idx += gsz) {
        int e = idx >> 6, c = idx & 63;
        int row; float val;
        if (e < cnt2) {
            int s = e2s[e], u = e2d[e];
            float nrm = dinv_of(deg[s]) * dinv_of(deg[u]);
            row = pos1[u];
            val = nrm * x[(size_t)s * CH + c];
        } else {
            int i = e - cnt2;
            int u = F1[i];
            float du = dinv_of(deg[u]);
            row = i;
            val = du * du * x[(size_t)u * CH + c];
        }
        atomicAdd(&agg1e[row * CH + c], val);
    }
}

// P5 (blocks 0..NP5-1): one F1 row per wave; h1 = relu(agg1e @ W1 + b1).
// agg1e reads cached (atomics complete pre-B4); h1 writes agent-scope.
__device__ __forceinline__ void phase_h1g(int blockId, int tid,
                                          const float* __restrict__ W1,
                                          const float* __restrict__ b1,
                                          const int* __restrict__ ctrl,
                                          const float* __restrict__ agg1e,
                                          float* __restrict__ h1,
                                          float (*a)[CH]) {
    int nf1 = min(ctrl[2], F1CAP);
    int w = tid >> 6, j = tid & 63;
    for (int i = blockId * NWAVE + w; i < nf1; i += NP5 * NWAVE) {
        a[w][j] = agg1e[i * CH + j];                // same-wave LDS RAW
        float sum = b1[j];
#pragma unroll
        for (int k = 0; k < CH; k++) sum += a[w][k] * W1[k * CH + j];
        st_agent_f(&h1[i * CH + j], fmaxf(sum, 0.f));
    }
}

// P6 (block 0): layer-2 agg (4 waves/endpoint) + @W2+b2, relu, fc, sigmoid.
// All reads cached (h1 complete pre-B5).
__device__ __forceinline__ void phase_tail(int tid,
                                           const float* __restrict__ h1,
                                           const int* __restrict__ deg,
                                           const int* __restrict__ pos1,
                                           const int* __restrict__ np_,
                                           const int* __restrict__ ctrl,
                                           const int* __restrict__ e1s,
                                           const int* __restrict__ e1d,
                                           const float* __restrict__ W2,
                                           const float* __restrict__ b2,
                                           const float* __restrict__ fcW,
                                           const float* __restrict__ fcb,
                                           float* __restrict__ out,
                                           float (*a2p)[CH], float (*a2)[CH],
                                           float* partial) {
    int w = tid >> 6, j = tid & 63;
    int t = w >> 2, sub = w & 3;          // 4 waves per endpoint
    int pp = np_[t];
    float dp = dinv_of(deg[pp]);
    float acc = (sub == 0) ? dp * dp * h1[pos1[pp] * CH + j] : 0.f;
    int cnt1 = min(ctrl[0], E1CAP);
    for (int e = sub; e < cnt1; e += 4) {
        if (e1d[e] == pp) {
            int s = e1s[e];
            acc += dinv_of(deg[s]) * dp * h1[pos1[s] * CH + j];
        }
    }
    a2p[w][j] = acc;
    __syncthreads();
    if (tid < 128) {
        int t2 = tid >> 6;
        a2[t2][j] = a2p[t2 * 4][j] + a2p[t2 * 4 + 1][j] +
                    a2p[t2 * 4 + 2][j] + a2p[t2 * 4 + 3][j];
    }
    __syncthreads();
    if (tid < 128) {
        int t2 = tid >> 6;
        float sum = b2[j];
#pragma unroll
        for (int k = 0; k < CH; k++) sum += a2[t2][k] * W2[k * CH + j];
        float v = fmaxf(sum, 0.f);
        float pr = v * fcW[t2 * CH + j];
        for (int off = 32; off > 0; off >>= 1) pr += __shfl_down(pr, off);
        if (j == 0) partial[t2] = pr;
    }
    __syncthreads();
    if (tid == 0) {
        float z = partial[0] + partial[1] + fcb[0];
        out[0] = 1.f / (1.f + expf(-z));
    }
}

__global__ __launch_bounds__(BLK, 1) void k_fused(Params p) {
    __shared__ float a[NWAVE][CH];
    __shared__ float a2p[NWAVE][CH];
    __shared__ float a2[2][CH];
    __shared__ float partial[2];
    const int gid = blockIdx.x * BLK + threadIdx.x;
    const int gsz = GRID * BLK;

    phase_e1f1(gid, gsz, p.src, p.dst, p.E, p.np_[0], p.np_[1], p.ctrl,
               p.e1s, p.e1d, p.bmF1, p.bmNd, p.F1, p.pos1);
    gbar(p.bar, 1);
    phase_e2(gid, gsz, p.src, p.dst, p.E, p.bmF1, p.bmNd, p.ctrl, p.e2s, p.e2d);
    gbar(p.bar, 2);
    phase_deg(gid, gsz, p.dst, p.E, p.bmNd, p.deg);
    gbar(p.bar, 3);
    phase_agg(gid, gsz, p.x, p.deg, p.pos1, p.ctrl, p.e2s, p.e2d, p.F1, p.agg1e);
    if (blockIdx.x >= NP5) {          // no P5/P6 duties: final arrival + exit
        gbar_arrive(p.bar, 5);
        return;
    }
    gbar(p.bar, 4);
    phase_h1g(blockIdx.x, threadIdx.x, p.W1, p.b1, p.ctrl, p.agg1e, p.h1, a);
    gbar_arrive(p.bar, 5);
    if (blockIdx.x != 0) return;
    gbar_wait(p.bar, 5);
    phase_tail(threadIdx.x, p.h1, p.deg, p.pos1, p.np_, p.ctrl, p.e1s, p.e1d,
               p.W2, p.b2, p.fcW, p.fcb, (float*)p.out, a2p, a2, partial);
}

extern "C" void kernel_launch(void* const* d_in, const int* in_sizes, int n_in,
                              void* d_out, int out_size, void* d_ws, size_t ws_size,
                              hipStream_t stream) {
    const float* x   = (const float*)d_in[0];
    const int*   ei  = (const int*)d_in[1];
    const int*   np_ = (const int*)d_in[2];

    const int N = in_sizes[0] / CH;
    const int E = in_sizes[1] / 2;
    const int bmN = (N + 31) / 32;

    char* w = (char*)d_ws;
    size_t off = 0;
    auto alloc = [&](size_t bytes) {
        size_t o = off;
        off = (off + bytes + 255) & ~((size_t)255);
        return o;
    };
    // --- zeroed region (~1.5 MB, fill engine): bar + ctrl + bitmaps + deg
    //     + agg1e ---
    size_t o_bar  = alloc((size_t)GRID * 16 * 4);   // 64B-strided flags
    size_t o_ctrl = alloc(64);                      // cnt_e1, cnt_e2, nf1
    size_t o_bmF1 = alloc((size_t)bmN * 4);
    size_t o_bmNd = alloc((size_t)bmN * 4);
    size_t o_deg  = alloc((size_t)N * 4);
    size_t o_agg  = alloc((size_t)F1CAP * CH * 4);
    size_t zero_end = off;
    // --- uninitialized region ---
    size_t o_pos  = alloc((size_t)N * 4);
    size_t o_e1s  = alloc((size_t)E1CAP * 4);
    size_t o_e1d  = alloc((size_t)E1CAP * 4);
    size_t o_F1   = alloc((size_t)F1CAP * 4);
    size_t o_e2s  = alloc((size_t)E2CAP * 4);
    size_t o_e2d  = alloc((size_t)E2CAP * 4);
    size_t o_h1   = alloc((size_t)F1CAP * CH * 4);
    (void)ws_size;

    Params p;
    p.x    = x;
    p.src  = ei;
    p.dst  = ei + E;
    p.np_  = np_;
    p.W1   = (const float*)d_in[3];
    p.b1   = (const float*)d_in[4];
    p.W2   = (const float*)d_in[5];
    p.b2   = (const float*)d_in[6];
    p.fcW  = (const float*)d_in[7];
    p.fcb  = (const float*)d_in[8];
    p.bar   = (int*)(w + o_bar);
    p.ctrl  = (int*)(w + o_ctrl);
    p.bmF1  = (unsigned*)(w + o_bmF1);
    p.bmNd  = (unsigned*)(w + o_bmNd);
    p.deg   = (int*)(w + o_deg);
    p.agg1e = (float*)(w + o_agg);
    p.pos1  = (int*)(w + o_pos);
    p.e1s   = (int*)(w + o_e1s);
    p.e1d   = (int*)(w + o_e1d);
    p.F1    = (int*)(w + o_F1);
    p.e2s   = (int*)(w + o_e2s);
    p.e2d   = (int*)(w + o_e2d);
    p.h1    = (float*)(w + o_h1);
    p.out  = (float*)d_out;
    p.E = E; p.N = N; p.bmN = bmN;

    (void)hipMemsetAsync(d_ws, 0, zero_end, stream);   // ~1.5 MB

    k_fused<<<GRID, BLK, 0, stream>>>(p);
}

// Round 10
// 122.048 us; speedup vs baseline: 1.4939x; 1.0417x over previous
//
#include <hip/hip_runtime.h>
#include <math.h>

// GCN link predictor, sparse-cone evaluation (round 12).
// Round-11 post-mortem: cached reads REGRESSED 47 -> 53 us (theory dead;
// reverted to R8's agent-scope read discipline). Revised model of R8's 47:
// scans are TWO-DEEP dependent latency chains (dst int4 load -> data-dep
// bitmap LLC lookup), ~6 serial iters/thread => ~5us/scan x3 + agg's 4-deep
// agent chain + 5 barriers x ~2us. This round (vs R8):
//  - bitmap copied to LDS per block after B1/B2: per-edge lookup 500ns->60cy
//  - batched dst loads (4 int4/iter, independent): 1 latency round per scan
//  - GRID 256 (1 block/CU): per-thread scan work halves again
//  - e1/e2 as packed 8B (s,d): one agent load, not two, in agg/tail chains
//
// Phases (one plain launch, 5 fenceless flag barriers):
//  P1  scan dst: e1 edges; register F1                       -- B1 --
//  P2  copy bmF1->LDS; scan dst: e2 edges; need-bits src     -- B2 --
//  P3  copy bmNd->LDS; scan dst: deg[d]++ if need-bit        -- B3 --
//  P4  edge-parallel agg incl. self-loop virtual edges       -- B4 --
//      (blocks >= 8 arrive with final flag and exit)
//  P5  per-F1-row GEMM on blocks 0..7                        -- B5 --
//  P6  block 0: layer-2 agg + @W2+b2, relu, fc, sigmoid

#define CH 64
#define E1CAP 4096
#define F1CAP (E1CAP + 2)
#define E2CAP 131072
#define GRID 256
#define BLK 512
#define NWAVE (BLK / 64)
#define NP5 8
#define BMCAP 3200
#define SPIN_MAX (1 << 20)

struct Params {
    const float* x;
    const int* src; const int* dst; const int* np_;
    const float* W1; const float* b1;
    const float* W2; const float* b2;
    const float* fcW; const float* fcb;
    int* bar;          // [16*b] = block b flag (64B stride), monotone
    int* ctrl;         // [0]=cnt_e1 [1]=cnt_e2 [2]=nf1
    int* deg;
    unsigned* bmF1; unsigned* bmNd;
    int* pos1; long long* e1sd; int* F1;
    long long* e2sd; float* h1; float* agg1e;
    float* out;
    int E; int N; int bmN;
};

__device__ __forceinline__ float dinv_of(int degv) {
    return rsqrtf((float)(degv + 1));
}

__device__ __forceinline__ void st_agent(int* p, int v) {
    __hip_atomic_store(p, v, __ATOMIC_RELAXED, __HIP_MEMORY_SCOPE_AGENT);
}
__device__ __forceinline__ void st_agent_f(float* p, float v) {
    __hip_atomic_store(p, v, __ATOMIC_RELAXED, __HIP_MEMORY_SCOPE_AGENT);
}
__device__ __forceinline__ void st_agent64(long long* p, long long v) {
    __hip_atomic_store(p, v, __ATOMIC_RELAXED, __HIP_MEMORY_SCOPE_AGENT);
}
__device__ __forceinline__ int ld_agent(const int* p) {
    return __hip_atomic_load((int*)p, __ATOMIC_RELAXED, __HIP_MEMORY_SCOPE_AGENT);
}
__device__ __forceinline__ long long ld_agent64(const long long* p) {
    return __hip_atomic_load((long long*)p, __ATOMIC_RELAXED, __HIP_MEMORY_SCOPE_AGENT);
}
__device__ __forceinline__ float ld_agent_f(const float* p) {
    return __hip_atomic_load((float*)p, __ATOMIC_RELAXED, __HIP_MEMORY_SCOPE_AGENT);
}

// Fenceless barrier (uncached-mutable discipline; see R10/R8 notes).
__device__ __forceinline__ void gbar_arrive(int* bar, int phase) {
    __syncthreads();
    if (threadIdx.x == 0) {
        asm volatile("" ::: "memory");
        st_agent(&bar[blockIdx.x << 4], phase);
    }
}
__device__ __forceinline__ void gbar_wait(int* bar, int phase) {
    if (threadIdx.x < 64) {
        const int l = threadIdx.x;
        for (int it = 0; ; ++it) {
            int a = ld_agent(&bar[l << 4]);
            int b = ld_agent(&bar[(l + 64) << 4]);
            int c = ld_agent(&bar[(l + 128) << 4]);
            int d = ld_agent(&bar[(l + 192) << 4]);
            if (__all(min(min(a, b), min(c, d)) >= phase) || it > SPIN_MAX) break;
            __builtin_amdgcn_s_sleep(1);
        }
    }
    __syncthreads();
}
__device__ __forceinline__ void gbar(int* bar, int phase) {
    gbar_arrive(bar, phase);
    gbar_wait(bar, phase);
}

__device__ __forceinline__ void reg_node(int u, unsigned* bmF1, unsigned* bmNd,
                                         int* ctrl, int* F1, int* pos1) {
    unsigned bit = 1u << (u & 31);
    unsigned old = atomicOr(&bmF1[u >> 5], bit);
    if (!(old & bit)) {
        atomicOr(&bmNd[u >> 5], bit);
        int i = atomicAdd(&ctrl[2], 1);
        st_agent(&F1[i], u);
        st_agent(&pos1[u], i);
    }
}

__device__ __forceinline__ long long pack_sd(int s, int d) {
    return ((long long)(unsigned)d << 32) | (unsigned)s;
}

// P1: batched scan; e1 collection + F1 registration.
__device__ __forceinline__ void phase_e1f1(int gid, int gsz,
                                           const int* __restrict__ src,
                                           const int* __restrict__ dst, int E,
                                           int p0, int p1, int* ctrl,
                                           long long* e1sd,
                                           unsigned* bmF1, unsigned* bmNd,
                                           int* F1, int* pos1) {
    if (gid == 0) {
        reg_node(p0, bmF1, bmNd, ctrl, F1, pos1);
        if (p1 != p0) reg_node(p1, bmF1, bmNd, ctrl, F1, pos1);
    }
    const int nvec = E >> 2;
    const int4* dst4 = (const int4*)dst;
    for (int base = gid; base < nvec; base += gsz * 4) {
        int4 v[4];
#pragma unroll
        for (int t = 0; t < 4; t++) {
            int i = base + t * gsz;
            if (i < nvec) v[t] = dst4[i];
        }
#pragma unroll
        for (int t = 0; t < 4; t++) {
            int i = base + t * gsz;
            if (i >= nvec) continue;
            int ds[4] = {v[t].x, v[t].y, v[t].z, v[t].w};
#pragma unroll
            for (int k = 0; k < 4; k++) {
                int d = ds[k];
                if (d == p0 || d == p1) {
                    int s = src[i * 4 + k];
                    int idx = atomicAdd(&ctrl[0], 1);
                    if (idx < E1CAP) st_agent64(&e1sd[idx], pack_sd(s, d));
                    reg_node(s, bmF1, bmNd, ctrl, F1, pos1);
                }
            }
        }
    }
    for (int e = (nvec << 2) + gid; e < E; e += gsz) {
        int d = dst[e];
        if (d == p0 || d == p1) {
            int s = src[e];
            int idx = atomicAdd(&ctrl[0], 1);
            if (idx < E1CAP) st_agent64(&e1sd[idx], pack_sd(s, d));
            reg_node(s, bmF1, bmNd, ctrl, F1, pos1);
        }
    }
}

// P2: bmF1 -> LDS, then batched scan; per-edge test is an LDS hit.
__device__ __forceinline__ void phase_e2(int tid, int gid, int gsz,
                                         const int* __restrict__ src,
                                         const int* __restrict__ dst, int E,
                                         const unsigned* __restrict__ bmF1,
                                         unsigned* bmNd, int* ctrl,
                                         long long* e2sd,
                                         unsigned* lbm, int bmN) {
    const bool lds_ok = (bmN <= BMCAP);
    if (lds_ok)
        for (int i = tid; i < bmN; i += BLK) lbm[i] = bmF1[i];
    __syncthreads();
    const int nvec = E >> 2;
    const int4* dst4 = (const int4*)dst;
    for (int base = gid; base < nvec; base += gsz * 4) {
        int4 v[4];
#pragma unroll
        for (int t = 0; t < 4; t++) {
            int i = base + t * gsz;
            if (i < nvec) v[t] = dst4[i];
        }
#pragma unroll
        for (int t = 0; t < 4; t++) {
            int i = base + t * gsz;
            if (i >= nvec) continue;
            int ds[4] = {v[t].x, v[t].y, v[t].z, v[t].w};
#pragma unroll
            for (int k = 0; k < 4; k++) {
                int d = ds[k];
                unsigned word;
                if (lds_ok) word = lbm[d >> 5]; else word = bmF1[d >> 5];
                if ((word >> (d & 31)) & 1u) {
                    int s = src[i * 4 + k];
                    atomicOr(&bmNd[s >> 5], 1u << (s & 31));
                    int idx = atomicAdd(&ctrl[1], 1);
                    if (idx < E2CAP) st_agent64(&e2sd[idx], pack_sd(s, d));
                }
            }
        }
    }
    for (int e = (nvec << 2) + gid; e < E; e += gsz) {
        int d = dst[e];
        unsigned word;
        if (lds_ok) word = lbm[d >> 5]; else word = bmF1[d >> 5];
        if ((word >> (d & 31)) & 1u) {
            int s = src[e];
            atomicOr(&bmNd[s >> 5], 1u << (s & 31));
            int idx = atomicAdd(&ctrl[1], 1);
            if (idx < E2CAP) st_agent64(&e2sd[idx], pack_sd(s, d));
        }
    }
}

// P3: bmNd -> LDS, then batched scan; deg count for need-set nodes.
__device__ __forceinline__ void phase_deg(int tid, int gid, int gsz,
                                          const int* __restrict__ dst, int E,
                                          const unsigned* __restrict__ bmNd,
                                          int* deg, unsigned* lbm, int bmN) {
    const bool lds_ok = (bmN <= BMCAP);
    if (lds_ok)
        for (int i = tid; i < bmN; i += BLK) lbm[i] = bmNd[i];
    __syncthreads();
    const int nvec = E >> 2;
    const int4* dst4 = (const int4*)dst;
    for (int base = gid; base < nvec; base += gsz * 4) {
        int4 v[4];
#pragma unroll
        for (int t = 0; t < 4; t++) {
            int i = base + t * gsz;
            if (i < nvec) v[t] = dst4[i];
        }
#pragma unroll
        for (int t = 0; t < 4; t++) {
            int i = base + t * gsz;
            if (i >= nvec) continue;
            int ds[4] = {v[t].x, v[t].y, v[t].z, v[t].w};
#pragma unroll
            for (int k = 0; k < 4; k++) {
                int d = ds[k];
                unsigned word;
                if (lds_ok) word = lbm[d >> 5]; else word = bmNd[d >> 5];
                if ((word >> (d & 31)) & 1u) atomicAdd(&deg[d], 1);
            }
        }
    }
    for (int e = (nvec << 2) + gid; e < E; e += gsz) {
        int d = dst[e];
        unsigned word;
        if (lds_ok) word = lbm[d >> 5]; else word = bmNd[d >> 5];
        if ((word >> (d & 31)) & 1u) atomicAdd(&deg[d], 1);
    }
}

// P4: edge-parallel aggregation incl. self-loop virtual edges.
// Chain: e2 pair (1 round) -> deg/pos1 (1 round, parallel) -> x row -> atomic.
__device__ __forceinline__ void phase_agg(int gid, int gsz,
                                          const float* __restrict__ x,
                                          const int* __restrict__ deg,
                                          const int* __restrict__ pos1,
                                          const int* __restrict__ ctrl,
                                          const long long* __restrict__ e2sd,
                                          const int* __restrict__ F1,
                                          float* __restrict__ agg1e) {
    int cnt2 = min(ld_agent(&ctrl[1]), E2CAP);
    int nf1  = min(ld_agent(&ctrl[2]), F1CAP);
    int total = (cnt2 + nf1) << 6;
    for (int idx = gid; idx < total; idx += gsz) {
        int e = idx >> 6, c = idx & 63;
        int row; float val;
        if (e < cnt2) {
            long long sd = ld_agent64(&e2sd[e]);
            int s = (int)(sd & 0xffffffffll), u = (int)(sd >> 32);
            float nrm = dinv_of(ld_agent(&deg[s])) * dinv_of(ld_agent(&deg[u]));
            row = ld_agent(&pos1[u]);
            val = nrm * x[(size_t)s * CH + c];
        } else {
            int i = e - cnt2;
            int u = ld_agent(&F1[i]);
            float du = dinv_of(ld_agent(&deg[u]));
            row = i;
            val = du * du * x[(size_t)u * CH + c];
        }
        atomicAdd(&agg1e[row * CH + c], val);
    }
}

// P5 (blocks 0..NP5-1): one F1 row per wave; h1 = relu(agg1e @ W1 + b1).
__device__ __forceinline__ void phase_h1g(int blockId, int tid,
                                          const float* __restrict__ W1,
                                          const float* __restrict__ b1,
                                          const int* __restrict__ ctrl,
                                          const float* __restrict__ agg1e,
                                          float* __restrict__ h1,
                                          float (*a)[CH]) {
    int nf1 = min(ld_agent(&ctrl[2]), F1CAP);
    int w = tid >> 6, j = tid & 63;
    for (int i = blockId * NWAVE + w; i < nf1; i += NP5 * NWAVE) {
        a[w][j] = ld_agent_f(&agg1e[i * CH + j]);   // same-wave LDS RAW
        float sum = b1[j];
#pragma unroll
        for (int k = 0; k < CH; k++) sum += a[w][k] * W1[k * CH + j];
        st_agent_f(&h1[i * CH + j], fmaxf(sum, 0.f));
    }
}

// P6 (block 0): layer-2 agg (4 waves/endpoint) + @W2+b2, relu, fc, sigmoid.
__device__ __forceinline__ void phase_tail(int tid,
                                           const float* __restrict__ h1,
                                           const int* __restrict__ deg,
                                           const int* __restrict__ pos1,
                                           const int* __restrict__ np_,
                                           const int* __restrict__ ctrl,
                                           const long long* __restrict__ e1sd,
                                           const float* __restrict__ W2,
                                           const float* __restrict__ b2,
                                           const float* __restrict__ fcW,
                                           const float* __restrict__ fcb,
                                           float* __restrict__ out,
                                           float (*a2p)[CH], float (*a2)[CH],
                                           float* partial) {
    int w = tid >> 6, j = tid & 63;
    int t = w >> 2, sub = w & 3;          // 4 waves per endpoint
    int pp = np_[t];
    float dp = dinv_of(ld_agent(&deg[pp]));
    float acc = (sub == 0)
        ? dp * dp * ld_agent_f(&h1[ld_agent(&pos1[pp]) * CH + j]) : 0.f;
    int cnt1 = min(ld_agent(&ctrl[0]), E1CAP);
    for (int e = sub; e < cnt1; e += 4) {
        long long sd = ld_agent64(&e1sd[e]);
        int s = (int)(sd & 0xffffffffll), d = (int)(sd >> 32);
        if (d == pp) {
            acc += dinv_of(ld_agent(&deg[s])) * dp *
                   ld_agent_f(&h1[ld_agent(&pos1[s]) * CH + j]);
        }
    }
    a2p[w][j] = acc;
    __syncthreads();
    if (tid < 128) {
        int t2 = tid >> 6;
        a2[t2][j] = a2p[t2 * 4][j] + a2p[t2 * 4 + 1][j] +
                    a2p[t2 * 4 + 2][j] + a2p[t2 * 4 + 3][j];
    }
    __syncthreads();
    if (tid < 128) {
        int t2 = tid >> 6;
        float sum = b2[j];
#pragma unroll
        for (int k = 0; k < CH; k++) sum += a2[t2][k] * W2[k * CH + j];
        float v = fmaxf(sum, 0.f);
        float pr = v * fcW[t2 * CH + j];
        for (int off = 32; off > 0; off >>= 1) pr += __shfl_down(pr, off);
        if (j == 0) partial[t2] = pr;
    }
    __syncthreads();
    if (tid == 0) {
        float z = partial[0] + partial[1] + fcb[0];
        out[0] = 1.f / (1.f + expf(-z));
    }
}

__global__ __launch_bounds__(BLK, 1) void k_fused(Params p) {
    __shared__ unsigned lbm[BMCAP];     // 12.8 KB bitmap mirror
    __shared__ float a[NWAVE][CH];
    __shared__ float a2p[NWAVE][CH];
    __shared__ float a2[2][CH];
    __shared__ float partial[2];
    const int gid = blockIdx.x * BLK + threadIdx.x;
    const int gsz = GRID * BLK;

    phase_e1f1(gid, gsz, p.src, p.dst, p.E, p.np_[0], p.np_[1], p.ctrl,
               p.e1sd, p.bmF1, p.bmNd, p.F1, p.pos1);
    gbar(p.bar, 1);
    phase_e2(threadIdx.x, gid, gsz, p.src, p.dst, p.E, p.bmF1, p.bmNd,
             p.ctrl, p.e2sd, lbm, p.bmN);
    gbar(p.bar, 2);
    phase_deg(threadIdx.x, gid, gsz, p.dst, p.E, p.bmNd, p.deg, lbm, p.bmN);
    gbar(p.bar, 3);
    phase_agg(gid, gsz, p.x, p.deg, p.pos1, p.ctrl, p.e2sd, p.F1, p.agg1e);
    if (blockIdx.x >= NP5) {          // no P5/P6 duties: final arrival + exit
        gbar_arrive(p.bar, 5);
        return;
    }
    gbar(p.bar, 4);
    phase_h1g(blockIdx.x, threadIdx.x, p.W1, p.b1, p.ctrl, p.agg1e, p.h1, a);
    gbar_arrive(p.bar, 5);
    if (blockIdx.x != 0) return;
    gbar_wait(p.bar, 5);
    phase_tail(threadIdx.x, p.h1, p.deg, p.pos1, p.np_, p.ctrl, p.e1sd,
               p.W2, p.b2, p.fcW, p.fcb, (float*)p.out, a2p, a2, partial);
}

extern "C" void kernel_launch(void* const* d_in, const int* in_sizes, int n_in,
                              void* d_out, int out_size, void* d_ws, size_t ws_size,
                              hipStream_t stream) {
    const float* x   = (const float*)d_in[0];
    const int*   ei  = (const int*)d_in[1];
    const int*   np_ = (const int*)d_in[2];

    const int N = in_sizes[0] / CH;
    const int E = in_sizes[1] / 2;
    const int bmN = (N + 31) / 32;

    char* w = (char*)d_ws;
    size_t off = 0;
    auto alloc = [&](size_t bytes) {
        size_t o = off;
        off = (off + bytes + 255) & ~((size_t)255);
        return o;
    };
    // --- zeroed region (~1.5 MB, fill engine): bar + ctrl + bitmaps + deg
    //     + agg1e ---
    size_t o_bar  = alloc((size_t)GRID * 16 * 4);   // 64B-strided flags
    size_t o_ctrl = alloc(64);                      // cnt_e1, cnt_e2, nf1
    size_t o_bmF1 = alloc((size_t)bmN * 4);
    size_t o_bmNd = alloc((size_t)bmN * 4);
    size_t o_deg  = alloc((size_t)N * 4);
    size_t o_agg  = alloc((size_t)F1CAP * CH * 4);
    size_t zero_end = off;
    // --- uninitialized region ---
    size_t o_pos  = alloc((size_t)N * 4);
    size_t o_e1sd = alloc((size_t)E1CAP * 8);
    size_t o_F1   = alloc((size_t)F1CAP * 4);
    size_t o_e2sd = alloc((size_t)E2CAP * 8);
    size_t o_h1   = alloc((size_t)F1CAP * CH * 4);
    (void)ws_size;

    Params p;
    p.x    = x;
    p.src  = ei;
    p.dst  = ei + E;
    p.np_  = np_;
    p.W1   = (const float*)d_in[3];
    p.b1   = (const float*)d_in[4];
    p.W2   = (const float*)d_in[5];
    p.b2   = (const float*)d_in[6];
    p.fcW  = (const float*)d_in[7];
    p.fcb  = (const float*)d_in[8];
    p.bar   = (int*)(w + o_bar);
    p.ctrl  = (int*)(w + o_ctrl);
    p.bmF1  = (unsigned*)(w + o_bmF1);
    p.bmNd  = (unsigned*)(w + o_bmNd);
    p.deg   = (int*)(w + o_deg);
    p.agg1e = (float*)(w + o_agg);
    p.pos1  = (int*)(w + o_pos);
    p.e1sd  = (long long*)(w + o_e1sd);
    p.F1    = (int*)(w + o_F1);
    p.e2sd  = (long long*)(w + o_e2sd);
    p.h1    = (float*)(w + o_h1);
    p.out  = (float*)d_out;
    p.E = E; p.N = N; p.bmN = bmN;

    (void)hipMemsetAsync(d_ws, 0, zero_end, stream);   // ~1.5 MB

    k_fused<<<GRID, BLK, 0, stream>>>(p);
}